// Round 1
// baseline (1181.341 us; speedup 1.0000x reference)
//
#include <hip/hip_runtime.h>
#include <math.h>

// Problem constants (from reference): B=256, LMAX=512, NCOND=300, NHID=600
#define BB      256
#define LMAX    512
#define NCOND   300
#define NHID    600
#define S_SPLIT 8            // split L range into 8 segments of 64 for load balance
#define LSEG    (LMAX / S_SPLIT)  // 64
#define TL      16           // token tile staged in LDS
#define NT      320          // threads per block (5 waves); 2 hidden cols/thread -> 640 slots for 600

// ---------------------------------------------------------------------------
// Kernel 1: fused  relu(ctx @ W1 + b1)  +  masked-sum pooling (per L-segment).
// partial layout: [S_SPLIT][B][NHID] in d_ws (8*256*600*4 = 4.9 MB).
// Only tokens l < max(len,1) are read/accumulated (halves the FLOPs vs dense).
// ---------------------------------------------------------------------------
__global__ __launch_bounds__(NT) void k1_pool_partial(
    const float* __restrict__ ctx, const int* __restrict__ lengths,
    const float* __restrict__ W1, const float* __restrict__ b1,
    float* __restrict__ partial)
{
    const int b   = blockIdx.x;
    const int s   = blockIdx.y;
    const int tid = threadIdx.x;

    int count = lengths[b];
    if (count < 1) count = 1;                 // reference clamps lens >= 1
    const int l0 = s * LSEG;
    const int l1 = min(l0 + LSEG, count);

    __shared__ float ctxs[TL * NCOND];        // 19.2 KB, rows contiguous (300 = 75 float4)

    const int  n0    = tid;                   // 0..319, always < 600
    const bool hasn1 = (tid < (NHID - NT));   // tid < 280
    const int  n1    = hasn1 ? tid + NT : 0;  // clamp to keep loads in-bounds

    float psum0 = 0.f, psum1 = 0.f;
    const float b1n0 = b1[n0];
    const float b1n1 = b1[n1];

    for (int t = l0; t < l1; t += TL) {
        const int nt = min(TL, l1 - t);

        // Stage nt contiguous context rows into LDS as float4 (base is 16B-aligned:
        // offsets are multiples of 300 floats and 300 % 4 == 0).
        const float4* src = (const float4*)(ctx + ((size_t)b * LMAX + t) * NCOND);
        float4*       dst = (float4*)ctxs;
        const int nvec = nt * (NCOND / 4);
        for (int i = tid; i < nvec; i += NT) dst[i] = src[i];
        __syncthreads();

        float acc0[TL], acc1[TL];
#pragma unroll
        for (int l = 0; l < TL; ++l) { acc0[l] = 0.f; acc1[l] = 0.f; }

        const float4* c4p = (const float4*)ctxs;
        for (int c4 = 0; c4 < NCOND / 4; ++c4) {
            const int crow = c4 * 4;
            // W1 is [NCOND][NHID], column reads coalesced across lanes; L2-resident (720 KB)
            const float w00 = W1[(size_t)(crow + 0) * NHID + n0];
            const float w01 = W1[(size_t)(crow + 1) * NHID + n0];
            const float w02 = W1[(size_t)(crow + 2) * NHID + n0];
            const float w03 = W1[(size_t)(crow + 3) * NHID + n0];
            const float w10 = W1[(size_t)(crow + 0) * NHID + n1];
            const float w11 = W1[(size_t)(crow + 1) * NHID + n1];
            const float w12 = W1[(size_t)(crow + 2) * NHID + n1];
            const float w13 = W1[(size_t)(crow + 3) * NHID + n1];
#pragma unroll
            for (int l = 0; l < TL; ++l) {
                const float4 cv = c4p[l * (NCOND / 4) + c4];  // broadcast ds_read_b128
                acc0[l] = fmaf(cv.x, w00, acc0[l]);
                acc0[l] = fmaf(cv.y, w01, acc0[l]);
                acc0[l] = fmaf(cv.z, w02, acc0[l]);
                acc0[l] = fmaf(cv.w, w03, acc0[l]);
                acc1[l] = fmaf(cv.x, w10, acc1[l]);
                acc1[l] = fmaf(cv.y, w11, acc1[l]);
                acc1[l] = fmaf(cv.z, w12, acc1[l]);
                acc1[l] = fmaf(cv.w, w13, acc1[l]);
            }
        }

        // bias + ReLU per token, accumulate only valid tokens of this tile
#pragma unroll
        for (int l = 0; l < TL; ++l) {
            if (l < nt) {
                psum0 += fmaxf(acc0[l] + b1n0, 0.f);
                psum1 += fmaxf(acc1[l] + b1n1, 0.f);
            }
        }
        __syncthreads();
    }

    // Every block writes its partial row (d_ws is poisoned before each launch).
    float* prow = partial + ((size_t)s * BB + b) * NHID;
    prow[tid] = psum0;
    if (hasn1) prow[tid + NT] = psum1;
}

// ---------------------------------------------------------------------------
// Kernel 2: reduce segment partials -> pooled/len -> sigmoid(pooled@Wa + ba) * x
// ---------------------------------------------------------------------------
__global__ __launch_bounds__(NT) void k2_gate(
    const float* __restrict__ x, const int* __restrict__ lengths,
    const float* __restrict__ partial, const float* __restrict__ Wa,
    const float* __restrict__ ba, float* __restrict__ out)
{
    const int b   = blockIdx.x;
    const int tid = threadIdx.x;

    int count = lengths[b];
    if (count < 1) count = 1;
    const float inv = 1.0f / (float)count;

    __shared__ float pooled[NHID];
    for (int h = tid; h < NHID; h += NT) {
        float s = 0.f;
#pragma unroll
        for (int sp = 0; sp < S_SPLIT; ++sp)
            s += partial[((size_t)sp * BB + b) * NHID + h];
        pooled[h] = s * inv;
    }
    __syncthreads();

    if (tid < NCOND) {
        const int n = tid;
        float acc = ba[n];
        const float4* p4 = (const float4*)pooled;
#pragma unroll 2
        for (int h4 = 0; h4 < NHID / 4; ++h4) {
            const float4 pv = p4[h4];
            const int hb = h4 * 4;
            acc = fmaf(pv.x, Wa[(size_t)(hb + 0) * NCOND + n], acc);
            acc = fmaf(pv.y, Wa[(size_t)(hb + 1) * NCOND + n], acc);
            acc = fmaf(pv.z, Wa[(size_t)(hb + 2) * NCOND + n], acc);
            acc = fmaf(pv.w, Wa[(size_t)(hb + 3) * NCOND + n], acc);
        }
        const float gate = 1.0f / (1.0f + expf(-acc));
        out[(size_t)b * NCOND + n] = gate * x[(size_t)b * NCOND + n];
    }
}

extern "C" void kernel_launch(void* const* d_in, const int* in_sizes, int n_in,
                              void* d_out, int out_size, void* d_ws, size_t ws_size,
                              hipStream_t stream)
{
    // setup_inputs() order: x, context, lengths, W1, b1, Wa, ba
    const float* x       = (const float*)d_in[0];
    const float* ctx     = (const float*)d_in[1];
    const int*   lengths = (const int*)  d_in[2];
    const float* W1      = (const float*)d_in[3];
    const float* b1      = (const float*)d_in[4];
    const float* Wa      = (const float*)d_in[5];
    const float* ba      = (const float*)d_in[6];
    float*       out     = (float*)d_out;
    float*       partial = (float*)d_ws;   // needs S_SPLIT*B*NHID*4 = 4.9 MB

    dim3 g1(BB, S_SPLIT);
    k1_pool_partial<<<g1, NT, 0, stream>>>(ctx, lengths, W1, b1, partial);
    k2_gate<<<BB, NT, 0, stream>>>(x, lengths, partial, Wa, ba, out);
}

// Round 2
// 340.004 us; speedup vs baseline: 3.4745x; 3.4745x over previous
//
#include <hip/hip_runtime.h>
#include <math.h>

// Problem constants: B=256, LMAX=512, NCOND=300, NHID=600
#define BB     256
#define LMAX   512
#define NCOND  300
#define NHID   600
#define NSEG   8          // 8 segments of 64 tokens
#define LSEG   64
#define KPAD   320        // K padded to 10 chunks of 32 (k>=300 is zero in W1T)
#define KLDS   328        // LDS row stride in bf16 elems: 656B = 16B-aligned, 4-bank shift/row
                          //   -> ds_read_b128 frag reads are perfectly even (8-phase floor)
#define NCOLP  640        // hidden padded to 40 tiles of 16 (cols>=600 zero, dropped at write)

typedef short s16x8 __attribute__((ext_vector_type(8)));  // 8 bf16 (4 VGPRs) - doc-verified frag type
typedef float f32x4 __attribute__((ext_vector_type(4)));  // MFMA accumulator

// fp32 -> bf16 round-to-nearest-even (inputs are finite)
__device__ inline unsigned short f2bf(float f) {
    unsigned int x = __float_as_uint(f);
    x += 0x7fffu + ((x >> 16) & 1u);
    return (unsigned short)(x >> 16);
}

// ---------------------------------------------------------------------------
// k0: build W1T bf16 [NCOLP][KPAD] from W1 fp32 [NCOND][NHID], zero-padded.
// ---------------------------------------------------------------------------
__global__ __launch_bounds__(256) void k0_w1t(const float* __restrict__ W1,
                                              unsigned short* __restrict__ w1t) {
    const int idx = blockIdx.x * 256 + threadIdx.x;
    if (idx >= NCOLP * KPAD) return;
    const int n = idx / KPAD;
    const int k = idx - n * KPAD;
    unsigned short v = 0;
    if (n < NHID && k < NCOND) v = f2bf(W1[(size_t)k * NHID + n]);
    w1t[idx] = v;
}

// ---------------------------------------------------------------------------
// k1: per (batch, 64-token segment, col-half 320): bf16 MFMA
//     h = relu(ctx@W1+b1), masked row-sum -> partial[seg][b][600]
// Block 256 thr = 4 waves; wave w owns cols [ch*320 + w*80, +80) = 5 N-tiles.
// Whole 64-token ctx segment staged once in LDS (bf16, K-padded with zeros).
// ---------------------------------------------------------------------------
__global__ __launch_bounds__(256, 3) void k1_mfma_pool(
    const float* __restrict__ ctx, const int* __restrict__ lengths,
    const unsigned short* __restrict__ w1t, const float* __restrict__ b1,
    float* __restrict__ partial)
{
    const int b    = blockIdx.x;
    const int s    = blockIdx.y;
    const int ch   = blockIdx.z;
    const int tid  = threadIdx.x;
    const int lane = tid & 63;
    const int wv   = tid >> 6;
    const int ln15 = lane & 15;   // MFMA: A row / B col / C col
    const int kg   = lane >> 4;   // MFMA: k-group (A/B), row-group (C)

    int count = lengths[b]; if (count < 1) count = 1;   // reference clamps lens >= 1
    const int l0   = s * LSEG;
    const int nrows = min(count - l0, LSEG);            // <=0 -> empty block, write zeros

    __shared__ __align__(16) unsigned short atile[LSEG * KLDS];  // 41,984 B

    const int colbase = ch * 320 + wv * 80;
    float psum[5] = {0.f, 0.f, 0.f, 0.f, 0.f};

    if (nrows > 0) {
        const int nmt = (nrows + 15) >> 4;   // 1..4 active M-tiles (block-uniform)

        // zero the K-pad [300,328) for all rows (protects valid rows: pad*0 must be 0, not NaN*0)
        {
            unsigned int* a32 = (unsigned int*)atile;
            for (int i = tid; i < LSEG * 14; i += 256) {
                const int r = i / 14, d = i - r * 14;
                a32[r * (KLDS / 2) + 150 + d] = 0u;
            }
        }
        // stage valid rows fp32 -> bf16 (rows >= nrows stay garbage; masked in epilogue)
        {
            const int nvec = nrows * 75;     // 75 float4 per row
            for (int i = tid; i < nvec; i += 256) {
                const int r = i / 75, c4 = i - r * 75;
                const float4 v = *(const float4*)(ctx + ((size_t)(b * LMAX + l0 + r)) * NCOND + c4 * 4);
                union { unsigned short us[4]; short4 s4; } u;
                u.us[0] = f2bf(v.x); u.us[1] = f2bf(v.y);
                u.us[2] = f2bf(v.z); u.us[3] = f2bf(v.w);
                *(short4*)(atile + r * KLDS + c4 * 4) = u.s4;
            }
        }
        __syncthreads();

        f32x4 acc[5][4];
#pragma unroll
        for (int nt = 0; nt < 5; ++nt)
#pragma unroll
            for (int mt = 0; mt < 4; ++mt) acc[nt][mt] = (f32x4){0.f, 0.f, 0.f, 0.f};

        const unsigned short* arow = atile + ln15 * KLDS + kg * 8;
        const unsigned short* brow = w1t + (size_t)(colbase + ln15) * KPAD + kg * 8;

        for (int kc = 0; kc < 10; ++kc) {
            s16x8 af[4];
#pragma unroll
            for (int mt = 0; mt < 4; ++mt)
                if (mt < nmt)   // block-uniform -> cheap s_cbranch, keeps acc static-indexed
                    af[mt] = *(const s16x8*)(arow + mt * 16 * KLDS + kc * 32);
#pragma unroll
            for (int nt = 0; nt < 5; ++nt) {
                const s16x8 bf = *(const s16x8*)(brow + nt * 16 * KPAD + kc * 32);
#pragma unroll
                for (int mt = 0; mt < 4; ++mt)
                    if (mt < nmt)
                        acc[nt][mt] = __builtin_amdgcn_mfma_f32_16x16x32_bf16(af[mt], bf, acc[nt][mt], 0, 0, 0);
            }
        }

        // epilogue: bias + ReLU + validity mask, reduce over the 16 rows of each tile
#pragma unroll
        for (int nt = 0; nt < 5; ++nt) {
            const int colg = colbase + nt * 16 + ln15;
            const float b1c = (colg < NHID) ? b1[colg] : 0.f;
            float ssum = 0.f;
#pragma unroll
            for (int mt = 0; mt < 4; ++mt) {
                if (mt < nmt) {
                    const int rbase = mt * 16 + kg * 4;
#pragma unroll
                    for (int r = 0; r < 4; ++r)
                        if (rbase + r < nrows)                     // masks garbage/invalid rows
                            ssum += fmaxf(acc[nt][mt][r] + b1c, 0.f);
                }
            }
            // sum the 4 row-groups (lanes with same ln15)
            ssum += __shfl_xor(ssum, 16, 64);
            ssum += __shfl_xor(ssum, 32, 64);
            psum[nt] = ssum;
        }
    }

    // write partial (zeros when the segment is empty; d_ws is poisoned each launch)
    if (kg == 0) {
#pragma unroll
        for (int nt = 0; nt < 5; ++nt) {
            const int colg = colbase + nt * 16 + ln15;
            if (colg < NHID)
                partial[((size_t)s * BB + b) * NHID + colg] = psum[nt];
        }
    }
}

// ---------------------------------------------------------------------------
// k2: reduce 8 segment partials -> pooled/len -> sigmoid(pooled@Wa + ba) * x
// grid (B, 2): each block computes 150 of the 300 output cols (occupancy/ILP).
// ---------------------------------------------------------------------------
__global__ __launch_bounds__(192) void k2_gate(
    const float* __restrict__ x, const int* __restrict__ lengths,
    const float* __restrict__ partial, const float* __restrict__ Wa,
    const float* __restrict__ ba, float* __restrict__ out)
{
    const int b    = blockIdx.x;
    const int half = blockIdx.y;
    const int tid  = threadIdx.x;

    int count = lengths[b]; if (count < 1) count = 1;
    const float inv = 1.0f / (float)count;

    __shared__ float pooled[NHID];
    for (int h = tid; h < NHID; h += 192) {
        float ssum = 0.f;
#pragma unroll
        for (int sp = 0; sp < NSEG; ++sp)
            ssum += partial[((size_t)sp * BB + b) * NHID + h];
        pooled[h] = ssum * inv;
    }
    __syncthreads();

    if (tid < 150) {
        const int n = half * 150 + tid;
        float a0 = ba[n], a1 = 0.f;   // 2-way ILP on the 600-long dot
        const float4* p4 = (const float4*)pooled;
        for (int h4 = 0; h4 < NHID / 4; h4 += 2) {
            const float4 pv0 = p4[h4];
            const float4 pv1 = p4[h4 + 1];
            const int hb = h4 * 4;
            a0 = fmaf(pv0.x, Wa[(size_t)(hb + 0) * NCOND + n], a0);
            a0 = fmaf(pv0.y, Wa[(size_t)(hb + 1) * NCOND + n], a0);
            a0 = fmaf(pv0.z, Wa[(size_t)(hb + 2) * NCOND + n], a0);
            a0 = fmaf(pv0.w, Wa[(size_t)(hb + 3) * NCOND + n], a0);
            a1 = fmaf(pv1.x, Wa[(size_t)(hb + 4) * NCOND + n], a1);
            a1 = fmaf(pv1.y, Wa[(size_t)(hb + 5) * NCOND + n], a1);
            a1 = fmaf(pv1.z, Wa[(size_t)(hb + 6) * NCOND + n], a1);
            a1 = fmaf(pv1.w, Wa[(size_t)(hb + 7) * NCOND + n], a1);
        }
        const float acc  = a0 + a1;
        const float gate = 1.0f / (1.0f + expf(-acc));
        out[(size_t)b * NCOND + n] = gate * x[(size_t)b * NCOND + n];
    }
}

extern "C" void kernel_launch(void* const* d_in, const int* in_sizes, int n_in,
                              void* d_out, int out_size, void* d_ws, size_t ws_size,
                              hipStream_t stream)
{
    // setup_inputs() order: x, context, lengths, W1, b1, Wa, ba
    const float* x       = (const float*)d_in[0];
    const float* ctx     = (const float*)d_in[1];
    const int*   lengths = (const int*)  d_in[2];
    const float* W1      = (const float*)d_in[3];
    const float* b1      = (const float*)d_in[4];
    const float* Wa      = (const float*)d_in[5];
    const float* ba      = (const float*)d_in[6];
    float*       out     = (float*)d_out;

    // ws layout: [W1T bf16 640*320 = 409,600 B][partial fp32 8*256*600 = 4,915,200 B]
    unsigned short* w1t     = (unsigned short*)d_ws;
    float*          partial = (float*)((char*)d_ws + (size_t)NCOLP * KPAD * sizeof(unsigned short));

    k0_w1t<<<(NCOLP * KPAD + 255) / 256, 256, 0, stream>>>(W1, w1t);
    k1_mfma_pool<<<dim3(BB, NSEG, 2), 256, 0, stream>>>(ctx, lengths, w1t, b1, partial);
    k2_gate<<<dim3(BB, 2), 192, 0, stream>>>(x, lengths, partial, Wa, ba, out);
}

// Round 3
// 320.151 us; speedup vs baseline: 3.6900x; 1.0620x over previous
//
#include <hip/hip_runtime.h>
#include <math.h>

// Problem constants: B=256, LMAX=512, NCOND=300, NHID=600
#define BB     256
#define LMAX   512
#define NCOND  300
#define NHID   600
#define KPAD   320        // K padded to 10 chunks of 32 (k>=300 zero in W1T)
#define KLDS   328        // LDS row stride (elems): 656 B, 16B-aligned, 4-bank shift/row
#define NCOLP  640        // hidden padded to 40 tiles of 16
#define NTILE  40
#define NKC    10         // KPAD/32
#define CHUNK  64         // rows staged per iteration

typedef short s16x8 __attribute__((ext_vector_type(8)));  // MFMA A/B frag (8 bf16)
typedef float f32x4 __attribute__((ext_vector_type(4)));  // MFMA accumulator

// fp32 -> bf16 round-to-nearest-even
__device__ inline unsigned short f2bf(float f) {
    unsigned int x = __float_as_uint(f);
    x += 0x7fffu + ((x >> 16) & 1u);
    return (unsigned short)(x >> 16);
}

// ---------------------------------------------------------------------------
// k0: (blocks 0..99)  build W1T bf16 in FRAGMENT-MAJOR layout:
//        w1t[((ntile*NKC + kc)*64 + lane)*8 + j] = B[k = kc*32+(lane>>4)*8+j][n = ntile*16+(lane&15)]
//     -> a wave's B-frag load is one contiguous 1 KB global_load_dwordx4.
//     (block 100)  longest-first schedule: sched[rank] = batch.
// ---------------------------------------------------------------------------
__global__ __launch_bounds__(256) void k0_prep(const float* __restrict__ W1,
                                               const int* __restrict__ lengths,
                                               unsigned short* __restrict__ w1t,
                                               int* __restrict__ sched)
{
    if (blockIdx.x < 100) {
        const int t     = blockIdx.x * 256 + threadIdx.x;  // 0..25599
        const int lane  = t & 63;
        const int g     = t >> 6;                          // 0..399 = ntile*NKC + kc
        const int ntile = g / NKC;
        const int kc    = g - ntile * NKC;
        const int n     = ntile * 16 + (lane & 15);
        const int kbase = kc * 32 + (lane >> 4) * 8;
        union { unsigned short us[8]; s16x8 v8; } u;
#pragma unroll
        for (int j = 0; j < 8; ++j) {
            const int k = kbase + j;
            const float w = (n < NHID && k < NCOND) ? W1[(size_t)k * NHID + n] : 0.f;
            u.us[j] = f2bf(w);
        }
        *(s16x8*)(w1t + (size_t)t * 8) = u.v8;             // 16B-aligned
    } else {
        // rank batches by clamped length, descending (unique ranks via index tiebreak)
        const int i = threadIdx.x;
        int li = lengths[i]; if (li < 1) li = 1;
        int rank = 0;
        for (int j = 0; j < BB; ++j) {
            int lj = lengths[j]; if (lj < 1) lj = 1;
            rank += (lj > li) || (lj == li && j < i);
        }
        sched[rank] = i;
    }
}

// ---------------------------------------------------------------------------
// k1: block = (sched[blockIdx>>1], col-half).  Loops 64-row chunks of ONE
//     batch; wave w owns cols [ch*320 + w*80, +80) = 5 N-tiles x 4 M-tiles.
//     kc loop fully unrolled with 2-deep register prefetch of A and B frags.
//     Writes pooled[b][col] = sum_valid relu(ctx@W1+b1) / len  directly.
// ---------------------------------------------------------------------------
__global__ __launch_bounds__(256) void k1_mfma_pool(
    const float* __restrict__ ctx, const int* __restrict__ lengths,
    const unsigned short* __restrict__ w1t, const float* __restrict__ b1,
    const int* __restrict__ sched, float* __restrict__ pooled)
{
    const int b    = sched[blockIdx.x >> 1];
    const int ch   = blockIdx.x & 1;
    const int tid  = threadIdx.x;
    const int lane = tid & 63;
    const int wv   = tid >> 6;
    const int ln15 = lane & 15;
    const int kg   = lane >> 4;

    int count = lengths[b]; if (count < 1) count = 1;
    const int nchunks = (count + CHUNK - 1) / CHUNK;

    __shared__ __align__(16) unsigned short atile[CHUNK * KLDS];   // 41,984 B

    const int ntile0 = ch * 20 + wv * 5;
    // wave-coalesced frag base: + nt*5120 elems per n-tile, + kc*512 per k-chunk
    const unsigned short* bbase = w1t + ((size_t)ntile0 * NKC * 64 + lane) * 8;
    const unsigned short* arow  = atile + ln15 * KLDS + kg * 8;

    // bias per n-tile (hoisted; cols >= NHID have zero B-cols -> psum stays 0)
    float b1c[5];
#pragma unroll
    for (int nt = 0; nt < 5; ++nt) {
        const int colg = ch * 320 + wv * 80 + nt * 16 + ln15;
        b1c[nt] = (colg < NHID) ? b1[colg] : 0.f;
    }

    float psum[5] = {0.f, 0.f, 0.f, 0.f, 0.f};

    for (int c = 0; c < nchunks; ++c) {
        const int l0    = c * CHUNK;
        const int valid = min(count - l0, CHUNK);

        // ---- stage 64 x KPAD bf16; rows >= valid and k >= 300 zero-filled.
        // 16B writes: lanes hit even 4-bank groups 2-way -> conflict-free.
#pragma unroll
        for (int p = 0; p < 10; ++p) {
            const int i  = p * 256 + tid;          // 0..2559
            const int r  = i / 40;
            const int c8 = i - r * 40;             // 8-elem column chunk
            union { unsigned short us[8]; s16x8 v8; } u;
            if (r < valid && c8 < 38) {
                const float* src = ctx + ((size_t)b * LMAX + l0 + r) * NCOND + c8 * 8;
                const float4 v0 = *(const float4*)src;
                float4 v1 = make_float4(0.f, 0.f, 0.f, 0.f);
                if (c8 < 37) v1 = *(const float4*)(src + 4);
                u.us[0] = f2bf(v0.x); u.us[1] = f2bf(v0.y);
                u.us[2] = f2bf(v0.z); u.us[3] = f2bf(v0.w);
                u.us[4] = f2bf(v1.x); u.us[5] = f2bf(v1.y);
                u.us[6] = f2bf(v1.z); u.us[7] = f2bf(v1.w);
            } else {
#pragma unroll
                for (int j = 0; j < 8; ++j) u.us[j] = 0;
            }
            *(s16x8*)(atile + r * KLDS + c8 * 8) = u.v8;
        }
        __syncthreads();

        // ---- MFMA over 10 k-chunks, fully unrolled, 2-deep prefetch
        f32x4 acc[5][4];
#pragma unroll
        for (int nt = 0; nt < 5; ++nt)
#pragma unroll
            for (int mt = 0; mt < 4; ++mt) acc[nt][mt] = (f32x4){0.f, 0.f, 0.f, 0.f};

        s16x8 bf[2][5], af[2][4];
#pragma unroll
        for (int nt = 0; nt < 5; ++nt) bf[0][nt] = *(const s16x8*)(bbase + nt * 5120);
#pragma unroll
        for (int mt = 0; mt < 4; ++mt) af[0][mt] = *(const s16x8*)(arow + mt * 16 * KLDS);

#pragma unroll
        for (int kc = 0; kc < NKC; ++kc) {
            const int cur = kc & 1, nxt = cur ^ 1;
            if (kc < NKC - 1) {
#pragma unroll
                for (int nt = 0; nt < 5; ++nt)
                    bf[nxt][nt] = *(const s16x8*)(bbase + nt * 5120 + (kc + 1) * 512);
#pragma unroll
                for (int mt = 0; mt < 4; ++mt)
                    af[nxt][mt] = *(const s16x8*)(arow + mt * 16 * KLDS + (kc + 1) * 32);
            }
#pragma unroll
            for (int nt = 0; nt < 5; ++nt)
#pragma unroll
                for (int mt = 0; mt < 4; ++mt)
                    acc[nt][mt] = __builtin_amdgcn_mfma_f32_16x16x32_bf16(
                        af[cur][mt], bf[cur][nt], acc[nt][mt], 0, 0, 0);
        }

        // ---- epilogue: bias + ReLU, mask rows >= valid, accumulate
#pragma unroll
        for (int nt = 0; nt < 5; ++nt) {
            float s = 0.f;
#pragma unroll
            for (int mt = 0; mt < 4; ++mt) {
                const int rbase = mt * 16 + kg * 4;
#pragma unroll
                for (int r = 0; r < 4; ++r) {
                    const float h = fmaxf(acc[nt][mt][r] + b1c[nt], 0.f);
                    if (rbase + r < valid) s += h;
                }
            }
            psum[nt] += s;
        }
        __syncthreads();   // atile reused next chunk
    }

    // ---- reduce across k-groups, divide by len, write pooled
    const float inv = 1.0f / (float)count;
#pragma unroll
    for (int nt = 0; nt < 5; ++nt) {
        float s = psum[nt];
        s += __shfl_xor(s, 16, 64);
        s += __shfl_xor(s, 32, 64);
        if (kg == 0) {
            const int colg = ch * 320 + wv * 80 + nt * 16 + ln15;
            if (colg < NHID)
                pooled[(size_t)b * NHID + colg] = s * inv;
        }
    }
}

// ---------------------------------------------------------------------------
// k2: gate = sigmoid(pooled @ Wa + ba); out = gate * x.   (92 MFLOP total)
// ---------------------------------------------------------------------------
__global__ __launch_bounds__(320) void k2_gate(
    const float* __restrict__ x, const float* __restrict__ pooled,
    const float* __restrict__ Wa, const float* __restrict__ ba,
    float* __restrict__ out)
{
    const int b   = blockIdx.x;
    const int tid = threadIdx.x;

    __shared__ float pl[NHID];
    for (int h = tid; h < NHID; h += 320)
        pl[h] = pooled[(size_t)b * NHID + h];
    __syncthreads();

    if (tid < NCOND) {
        const int n = tid;
        float a0 = ba[n], a1 = 0.f;
        const float4* p4 = (const float4*)pl;
        for (int h4 = 0; h4 < NHID / 4; h4 += 2) {
            const float4 pv0 = p4[h4];
            const float4 pv1 = p4[h4 + 1];
            const int hb = h4 * 4;
            a0 = fmaf(pv0.x, Wa[(size_t)(hb + 0) * NCOND + n], a0);
            a0 = fmaf(pv0.y, Wa[(size_t)(hb + 1) * NCOND + n], a0);
            a0 = fmaf(pv0.z, Wa[(size_t)(hb + 2) * NCOND + n], a0);
            a0 = fmaf(pv0.w, Wa[(size_t)(hb + 3) * NCOND + n], a0);
            a1 = fmaf(pv1.x, Wa[(size_t)(hb + 4) * NCOND + n], a1);
            a1 = fmaf(pv1.y, Wa[(size_t)(hb + 5) * NCOND + n], a1);
            a1 = fmaf(pv1.z, Wa[(size_t)(hb + 6) * NCOND + n], a1);
            a1 = fmaf(pv1.w, Wa[(size_t)(hb + 7) * NCOND + n], a1);
        }
        const float acc  = a0 + a1;
        const float gate = 1.0f / (1.0f + expf(-acc));
        out[(size_t)b * NCOND + n] = gate * x[(size_t)b * NCOND + n];
    }
}

extern "C" void kernel_launch(void* const* d_in, const int* in_sizes, int n_in,
                              void* d_out, int out_size, void* d_ws, size_t ws_size,
                              hipStream_t stream)
{
    // setup_inputs() order: x, context, lengths, W1, b1, Wa, ba
    const float* x       = (const float*)d_in[0];
    const float* ctx     = (const float*)d_in[1];
    const int*   lengths = (const int*)  d_in[2];
    const float* W1      = (const float*)d_in[3];
    const float* b1      = (const float*)d_in[4];
    const float* Wa      = (const float*)d_in[5];
    const float* ba      = (const float*)d_in[6];
    float*       out     = (float*)d_out;

    // ws layout: [w1t frag-major bf16: 640*320*2 = 409,600 B][sched: 1 KB][pooled: 614,400 B]
    unsigned short* w1t    = (unsigned short*)d_ws;
    int*            sched  = (int*)((char*)d_ws + 409600);
    float*          pooled = (float*)((char*)d_ws + 409600 + 1024);

    k0_prep<<<101, 256, 0, stream>>>(W1, lengths, w1t, sched);
    k1_mfma_pool<<<512, 256, 0, stream>>>(ctx, lengths, w1t, b1, sched, pooled);
    k2_gate<<<BB, 320, 0, stream>>>(x, pooled, Wa, ba, out);
}

// Round 5
// 298.819 us; speedup vs baseline: 3.9534x; 1.0714x over previous
//
#include <hip/hip_runtime.h>
#include <math.h>

// Problem constants: B=256, LMAX=512, NCOND=300, NHID=600
#define BB     256
#define LMAX   512
#define NCOND  300
#define NHID   600
#define NSEG   8          // 8 segments of 64 tokens; block = one segment chunk
#define CHUNK  64
#define KPAD   320        // K padded to 10 chunks of 32 (k>=300 zero in W1T)
#define KLDS   328        // LDS row stride (elems): 656 B, 16B-aligned, 2-way bank alias = free
#define NCOLP  640        // hidden padded to 40 tiles of 16
#define NKC    10         // KPAD/32

typedef short s16x8 __attribute__((ext_vector_type(8)));  // MFMA A/B frag (8 bf16)
typedef float f32x4 __attribute__((ext_vector_type(4)));  // MFMA accumulator

// fp32 -> bf16 round-to-nearest-even
__device__ inline unsigned short f2bf(float f) {
    unsigned int x = __float_as_uint(f);
    x += 0x7fffu + ((x >> 16) & 1u);
    return (unsigned short)(x >> 16);
}

// ---------------------------------------------------------------------------
// k0: build W1T bf16 in FRAGMENT-MAJOR layout:
//   w1t[((ntile*NKC + kc)*64 + lane)*8 + j] = W1[kc*32+(lane>>4)*8+j][ntile*16+(lane&15)]
// -> a wave's B-frag load is one contiguous 1 KB global_load_dwordx4.
// ---------------------------------------------------------------------------
__global__ __launch_bounds__(256) void k0_w1t(const float* __restrict__ W1,
                                              unsigned short* __restrict__ w1t)
{
    const int t     = blockIdx.x * 256 + threadIdx.x;  // 0..25599
    const int lane  = t & 63;
    const int g     = t >> 6;                          // ntile*NKC + kc
    const int ntile = g / NKC;
    const int kc    = g - ntile * NKC;
    const int n     = ntile * 16 + (lane & 15);
    const int kbase = kc * 32 + (lane >> 4) * 8;
    union { unsigned short us[8]; s16x8 v8; } u;
#pragma unroll
    for (int j = 0; j < 8; ++j) {
        const int k = kbase + j;
        const float w = (n < NHID && k < NCOND) ? W1[(size_t)k * NHID + n] : 0.f;
        u.us[j] = f2bf(w);
    }
    *(s16x8*)(w1t + (size_t)t * 8) = u.v8;
}

// ---------------------------------------------------------------------------
// k1: grid (BB, NSEG, 2). Block = ONE 64-row chunk of one batch, one col-half.
//     Uniform work per live block -> no tail; ~2300 live blocks, 3 blocks/CU.
//     partial[s][b][col] = sum over valid rows of relu(ctx@W1+b1)  (no /len).
// ---------------------------------------------------------------------------
__global__ __launch_bounds__(256, 3) void k1_mfma_pool(
    const float* __restrict__ ctx, const int* __restrict__ lengths,
    const unsigned short* __restrict__ w1t, const float* __restrict__ b1,
    float* __restrict__ partial)
{
    const int b  = blockIdx.x;
    const int s  = blockIdx.y;
    const int ch = blockIdx.z;

    int count = lengths[b]; if (count < 1) count = 1;   // reference clamps lens >= 1
    const int l0 = s * CHUNK;
    if (l0 >= count) return;                            // empty segment: no work, no write
    const int valid = min(count - l0, CHUNK);

    const int tid  = threadIdx.x;
    const int lane = tid & 63;
    const int wv   = tid >> 6;
    const int ln15 = lane & 15;
    const int kg   = lane >> 4;

    __shared__ __align__(16) unsigned short atile[CHUNK * KLDS];   // 41,984 B

    // ---- stage 64 x KPAD bf16; rows >= valid and k >= 300 zero-filled.
#pragma unroll
    for (int p = 0; p < 10; ++p) {
        const int i  = p * 256 + tid;          // 0..2559
        const int r  = i / 40;
        const int c8 = i - r * 40;             // 8-elem column chunk
        union { unsigned short us[8]; s16x8 v8; } u;
        if (r < valid && c8 < 38) {
            const float* src = ctx + ((size_t)b * LMAX + l0 + r) * NCOND + c8 * 8;
            const float4 v0 = *(const float4*)src;
            float4 v1 = make_float4(0.f, 0.f, 0.f, 0.f);
            if (c8 < 37) v1 = *(const float4*)(src + 4);
            u.us[0] = f2bf(v0.x); u.us[1] = f2bf(v0.y);
            u.us[2] = f2bf(v0.z); u.us[3] = f2bf(v0.w);
            u.us[4] = f2bf(v1.x); u.us[5] = f2bf(v1.y);
            u.us[6] = f2bf(v1.z); u.us[7] = f2bf(v1.w);
        } else {
#pragma unroll
            for (int j = 0; j < 8; ++j) u.us[j] = 0;
        }
        *(s16x8*)(atile + r * KLDS + c8 * 8) = u.v8;
    }
    __syncthreads();

    // ---- MFMA: wave wv owns cols [ch*320 + wv*80, +80) = 5 n-tiles x 4 m-tiles
    const int ntile0 = ch * 20 + wv * 5;
    const unsigned short* bbase = w1t + ((size_t)ntile0 * NKC * 64 + lane) * 8;
    const unsigned short* arow  = atile + ln15 * KLDS + kg * 8;

    f32x4 acc[5][4];
#pragma unroll
    for (int nt = 0; nt < 5; ++nt)
#pragma unroll
        for (int mt = 0; mt < 4; ++mt) acc[nt][mt] = (f32x4){0.f, 0.f, 0.f, 0.f};

    s16x8 bf[2][5];
#pragma unroll
    for (int nt = 0; nt < 5; ++nt) bf[0][nt] = *(const s16x8*)(bbase + nt * 5120);

#pragma unroll
    for (int kc = 0; kc < NKC; ++kc) {
        const int cur = kc & 1, nxt = cur ^ 1;
        if (kc < NKC - 1) {
#pragma unroll
            for (int nt = 0; nt < 5; ++nt)
                bf[nxt][nt] = *(const s16x8*)(bbase + nt * 5120 + (kc + 1) * 512);
        }
        s16x8 af[4];
#pragma unroll
        for (int mt = 0; mt < 4; ++mt)
            af[mt] = *(const s16x8*)(arow + mt * 16 * KLDS + kc * 32);
#pragma unroll
        for (int nt = 0; nt < 5; ++nt)
#pragma unroll
            for (int mt = 0; mt < 4; ++mt)
                acc[nt][mt] = __builtin_amdgcn_mfma_f32_16x16x32_bf16(
                    af[mt], bf[cur][nt], acc[nt][mt], 0, 0, 0);
    }

    // ---- epilogue: bias + ReLU, mask rows >= valid, reduce k-groups, write
#pragma unroll
    for (int nt = 0; nt < 5; ++nt) {
        const int colg = ch * 320 + wv * 80 + nt * 16 + ln15;
        const float b1c = (colg < NHID) ? b1[colg] : 0.f;
        float ssum = 0.f;
#pragma unroll
        for (int mt = 0; mt < 4; ++mt) {
            const int rbase = mt * 16 + kg * 4;
#pragma unroll
            for (int r = 0; r < 4; ++r) {
                const float h = fmaxf(acc[nt][mt][r] + b1c, 0.f);
                if (rbase + r < valid) ssum += h;
            }
        }
        ssum += __shfl_xor(ssum, 16, 64);
        ssum += __shfl_xor(ssum, 32, 64);
        if (kg == 0 && colg < NHID)
            partial[((size_t)s * BB + b) * NHID + colg] = ssum;
    }
}

// ---------------------------------------------------------------------------
// k2: 2 batches per block (same-n lanes share Wa loads). Reduce partials over
//     sp < ceil(len/64) (others unwritten/poisoned -> skipped), /len, then
//     gate = sigmoid(pooled@Wa + ba); out = gate * x.
// NOTE: NHID/4 = 150 float4s = 37*4 + 2 -> 4-wide main loop to h4<148, then
//       a 2-float4 tail. (Round 4 bug: stepping 4 to 150 overran pl AND Wa.)
// ---------------------------------------------------------------------------
__global__ __launch_bounds__(640) void k2_gate(
    const float* __restrict__ x, const int* __restrict__ lengths,
    const float* __restrict__ partial, const float* __restrict__ Wa,
    const float* __restrict__ ba, float* __restrict__ out)
{
    const int b0  = blockIdx.x * 2;
    const int tid = threadIdx.x;

    __shared__ float pl[2][NHID];

    if (tid < NHID) {
#pragma unroll
        for (int bb = 0; bb < 2; ++bb) {
            int count = lengths[b0 + bb]; if (count < 1) count = 1;
            const int nch = (count + CHUNK - 1) >> 6;
            float ssum = 0.f;
            for (int sp = 0; sp < nch; ++sp)
                ssum += partial[((size_t)sp * BB + (b0 + bb)) * NHID + tid];
            pl[bb][tid] = ssum / (float)count;
        }
    }
    __syncthreads();

    if (tid < 2 * NCOND) {
        const int bb = tid / NCOND;        // 0 or 1
        const int n  = tid - bb * NCOND;   // lanes 0..299 and 300..599 share Wa addrs
        const int b  = b0 + bb;
        float a0 = ba[n], a1 = 0.f, a2 = 0.f, a3 = 0.f;
        const float4* p4 = (const float4*)pl[bb];
        for (int h4 = 0; h4 < 148; h4 += 4) {   // h = 0..591
            const float4 pv0 = p4[h4];
            const float4 pv1 = p4[h4 + 1];
            const float4 pv2 = p4[h4 + 2];
            const float4 pv3 = p4[h4 + 3];
            const int hb = h4 * 4;
            a0 = fmaf(pv0.x, Wa[(size_t)(hb +  0) * NCOND + n], a0);
            a0 = fmaf(pv0.y, Wa[(size_t)(hb +  1) * NCOND + n], a0);
            a0 = fmaf(pv0.z, Wa[(size_t)(hb +  2) * NCOND + n], a0);
            a0 = fmaf(pv0.w, Wa[(size_t)(hb +  3) * NCOND + n], a0);
            a1 = fmaf(pv1.x, Wa[(size_t)(hb +  4) * NCOND + n], a1);
            a1 = fmaf(pv1.y, Wa[(size_t)(hb +  5) * NCOND + n], a1);
            a1 = fmaf(pv1.z, Wa[(size_t)(hb +  6) * NCOND + n], a1);
            a1 = fmaf(pv1.w, Wa[(size_t)(hb +  7) * NCOND + n], a1);
            a2 = fmaf(pv2.x, Wa[(size_t)(hb +  8) * NCOND + n], a2);
            a2 = fmaf(pv2.y, Wa[(size_t)(hb +  9) * NCOND + n], a2);
            a2 = fmaf(pv2.z, Wa[(size_t)(hb + 10) * NCOND + n], a2);
            a2 = fmaf(pv2.w, Wa[(size_t)(hb + 11) * NCOND + n], a2);
            a3 = fmaf(pv3.x, Wa[(size_t)(hb + 12) * NCOND + n], a3);
            a3 = fmaf(pv3.y, Wa[(size_t)(hb + 13) * NCOND + n], a3);
            a3 = fmaf(pv3.z, Wa[(size_t)(hb + 14) * NCOND + n], a3);
            a3 = fmaf(pv3.w, Wa[(size_t)(hb + 15) * NCOND + n], a3);
        }
        {   // tail: h = 592..599
            const float4 pv0 = p4[148];
            const float4 pv1 = p4[149];
            a0 = fmaf(pv0.x, Wa[(size_t)592 * NCOND + n], a0);
            a0 = fmaf(pv0.y, Wa[(size_t)593 * NCOND + n], a0);
            a0 = fmaf(pv0.z, Wa[(size_t)594 * NCOND + n], a0);
            a0 = fmaf(pv0.w, Wa[(size_t)595 * NCOND + n], a0);
            a1 = fmaf(pv1.x, Wa[(size_t)596 * NCOND + n], a1);
            a1 = fmaf(pv1.y, Wa[(size_t)597 * NCOND + n], a1);
            a1 = fmaf(pv1.z, Wa[(size_t)598 * NCOND + n], a1);
            a1 = fmaf(pv1.w, Wa[(size_t)599 * NCOND + n], a1);
        }
        const float acc  = (a0 + a1) + (a2 + a3);
        const float gate = 1.0f / (1.0f + expf(-acc));
        out[(size_t)b * NCOND + n] = gate * x[(size_t)b * NCOND + n];
    }
}

extern "C" void kernel_launch(void* const* d_in, const int* in_sizes, int n_in,
                              void* d_out, int out_size, void* d_ws, size_t ws_size,
                              hipStream_t stream)
{
    // setup_inputs() order: x, context, lengths, W1, b1, Wa, ba
    const float* x       = (const float*)d_in[0];
    const float* ctx     = (const float*)d_in[1];
    const int*   lengths = (const int*)  d_in[2];
    const float* W1      = (const float*)d_in[3];
    const float* b1      = (const float*)d_in[4];
    const float* Wa      = (const float*)d_in[5];
    const float* ba      = (const float*)d_in[6];
    float*       out     = (float*)d_out;

    // ws layout: [w1t frag-major bf16: 409,600 B][partial fp32 8*256*600: 4,915,200 B]
    unsigned short* w1t     = (unsigned short*)d_ws;
    float*          partial = (float*)((char*)d_ws + 409600);

    k0_w1t<<<100, 256, 0, stream>>>(W1, w1t);
    k1_mfma_pool<<<dim3(BB, NSEG, 2), 256, 0, stream>>>(ctx, lengths, w1t, b1, partial);
    k2_gate<<<BB / 2, 640, 0, stream>>>(x, lengths, partial, Wa, ba, out);
}